// Round 17
// baseline (83.799 us; speedup 1.0000x reference)
//
#include <hip/hip_runtime.h>

#define BB 2048
#define TT 4096
#define TQ (TT / 4)   // 1024 packed rows
#define K1C 0.00975461f   // 0.25*(4/9)^4  (Perc/X1 = K1C*z^5)

typedef __attribute__((ext_vector_type(4))) _Float16 half4;

// keep-alive. MUST be applied at CONSUMPTION time (R11: holding at load time
// forces vmcnt-wait per load and serializes everything).
#define HOLD2(U) asm volatile("" : "+v"((U).x), "+v"((U).y))

// ---------------------------------------------------------------------------
// Kernel 1: block 0 = r-chain closed form (X2==0: u=rn^-4 is exactly linear,
// rn_t=(u0+t)^-1/4 -> fully parallel; R16-validated). Blocks 1..2048: input
// tile staged raw into LDS via async global_load_lds (no VGPR destination ->
// compiler cannot serialize the 12-deep load batch; single vmcnt drain at the
// barrier), PET computed from LDS, fp16 w-tile written into the SAME aliased
// LDS, then packed-transposed wTh[tq][b] + per-8-step pilot sums.
// ---------------------------------------------------------------------------
__global__ __launch_bounds__(256) void precompute_kernel(
    const float* __restrict__ inp, const float* __restrict__ x1p,
    const float* __restrict__ x2p, const float* __restrict__ x3p,
    half4* __restrict__ wTh, half4* __restrict__ sumsh,
    float* __restrict__ qr) {

    if (blockIdx.x == 0) {
        float X2 = x2p[0] * 40.0f - 20.0f;
        float X3 = fminf(fmaxf(x3p[0], 1.0f / 300.0f), 1.0f) * 300.0f;
        if (X2 == 0.0f) {
            float rn0 = 0.7f;
            float rn2 = rn0 * rn0;
            float u0  = 1.0f / (rn2 * rn2);      // 0.7^-4
#pragma unroll
            for (int i = 0; i < 16; ++i) {
                int t = threadIdx.x + 256 * i;
                float v  = u0 + (float)t;
                float q  = __builtin_amdgcn_rcpf(v);
                float h  = fmaf(q, fmaf(q, fmaf(q, -0.09521484f,
                                  0.1171875f), -0.15625f), 0.25f);
                float w  = q * h;
                float rn = __builtin_amdgcn_rsqf(sqrtf(v));   // v^-1/4
                qr[t] = (X3 * rn) * w;
            }
        } else if (threadIdx.x == 0) {
            float invX3 = 1.0f / X3;
            float r = 0.7f * X3;
            for (int t = 0; t < TT; ++t) {
                float rx  = r * invX3;
                float rx3 = rx * rx * rx;
                float pw  = rx3 * sqrtf(rx);              // rx^3.5
                float r1  = fmaxf(fmaf(X2, pw, r), 0.0f);
                float m   = r1 * invX3;
                float m2  = m * m;
                float z   = fmaf(m2, m2, 1.0f);
                float u   = __builtin_amdgcn_rsqf(sqrtf(z)); // z^-0.25
                float Qr  = r1 * (1.0f - u);
                r = fminf(r1 * u, X3);
                qr[t] = Qr;
            }
        }
        return;
    }

    // 48 KB raw staging buffer; fp16 w-tile (8.7 KB) aliases its start.
    __shared__ char rawb[49152];
    float*    raw  = (float*)rawb;
    _Float16* ldsh = (_Float16*)rawb;

    const int bid = blockIdx.x - 1;
    const int tiles_t = TT / 64;                 // 64
    const int t0 = (bid % tiles_t) * 64;
    const int b0 = (bid / tiles_t) * 64;
    const float X1 = fminf(fmaxf(x1p[0], 1.0f / 2000.0f), 1.0f) * 2000.0f;
    const float invX1 = 1.0f / X1;

    // ---- phase 1a: async-stage the 48 KB tile (64 rows x 768 B) ----
    // LDS chunk c (1024 B) <- global bytes [o, o+1024) of the packed tile,
    // o = 1024c + 16*lane; row = o/768, within = o%768 (global rows are
    // 49152 B apart). LDS dest is wave-uniform base + lane*16 (HW rule).
    {
        const int wid  = threadIdx.x >> 6;
        const int lane = threadIdx.x & 63;
        const char* gbase = (const char*)inp +
                            12ull * ((size_t)b0 * TT + t0);
#pragma unroll
        for (int j = 0; j < 12; ++j) {
            int chunk = 12 * wid + j;
            int o   = 1024 * chunk + 16 * lane;
            int row = o / 768;
            int wi  = o - row * 768;
            const char* g = gbase + (size_t)row * 49152 + wi;
            char* l = rawb + 1024 * chunk;       // wave-uniform
            __builtin_amdgcn_global_load_lds(
                (const __attribute__((address_space(1))) void*)g,
                (__attribute__((address_space(3))) void*)l, 16, 0, 0);
        }
    }
    __syncthreads();                             // single vmcnt drain

    // ---- phase 1b: PET from LDS -> w in registers ----
    // thread -> (q = 4-t-group 0..15, r = row 0..15); 4 row-jobs each.
    const int q = threadIdx.x & 15;
    const int r = threadIdx.x >> 4;              // 0..15
    half4 hw[4];
#pragma unroll
    for (int i = 0; i < 4; ++i) {
        int bl = r + 16 * i;
        const float* rowp = raw + 192 * bl + 12 * q;  // 16B-aligned
        float4 A4 = *reinterpret_cast<const float4*>(rowp);
        float4 B4 = *reinterpret_cast<const float4*>(rowp + 4);
        float4 C4 = *reinterpret_cast<const float4*>(rowp + 8);
        // elements: p0 t0 d0 p1 | t1 d1 p2 t2 | d2 p3 t3 d3
        float pk[4], tk[4], dk[4];
        pk[0] = A4.x; tk[0] = A4.y; dk[0] = A4.z;
        pk[1] = A4.w; tk[1] = B4.x; dk[1] = B4.y;
        pk[2] = B4.z; tk[2] = B4.w; dk[2] = C4.x;
        pk[3] = C4.y; tk[3] = C4.z; dk[3] = C4.w;
#pragma unroll
        for (int j = 0; j < 4; ++j) {
            float tt = tk[j];
            float u1 = __builtin_amdgcn_rcpf(tt + 237.3f);
            float u2 = __builtin_amdgcn_rcpf(tt + 273.2f);
            float ex = exp2f((24.9586242f * tt) * u1);    // e^(17.3t/(t+237.3))
            float pet = (436.9872f * dk[j]) * (ex * u2);  // 29.8*24*0.611
            float w = (pk[j] - pet) * invX1;     // sign encodes cond
            if (j == 0) hw[i].x = (_Float16)w;
            else if (j == 1) hw[i].y = (_Float16)w;
            else if (j == 2) hw[i].z = (_Float16)w;
            else hw[i].w = (_Float16)w;
        }
    }
    __syncthreads();                             // all raw reads done
#pragma unroll
    for (int i = 0; i < 4; ++i) {
        int bl = r + 16 * i;
        *reinterpret_cast<half4*>(&ldsh[bl * 68 + 4 * q]) = hw[i];
    }
    __syncthreads();

    // ---- phase 2: wTh copy (already fp16) + pilot sums ----
    const int tl = threadIdx.x & 63;
    const int r4 = threadIdx.x >> 6;             // 0..3
    const int tq0 = t0 >> 2;
    for (int i = 0; i < 4; ++i) {
        int tr = i * 4 + r4;
        half4 hv = *reinterpret_cast<const half4*>(&ldsh[tl * 68 + tr * 4]);
        wTh[(size_t)(tq0 + tr) * BB + (b0 + tl)] = hv;
    }
#pragma unroll
    for (int i = 0; i < 2; ++i) {
        int job = threadIdx.x + 256 * i;         // 0..511
        int bl = job & 63, g = job >> 6;
        half4 ha = *reinterpret_cast<const half4*>(&ldsh[bl * 68 + g * 8]);
        half4 hb = *reinterpret_cast<const half4*>(&ldsh[bl * 68 + g * 8 + 4]);
        float s1 = 0.f, s2 = 0.f, s3 = 0.f, s4 = 0.f;
#pragma unroll
        for (int j = 0; j < 8; ++j) {
            float w = (j < 4) ? (float)((j == 0) ? ha.x : (j == 1) ? ha.y :
                                        (j == 2) ? ha.z : ha.w)
                              : (float)((j == 4) ? hb.x : (j == 5) ? hb.y :
                                        (j == 6) ? hb.z : hb.w);
            float a = fabsf(w);
            s1 += w; s2 += a; s3 += w * a; s4 += w * w;
        }
        half4 sh;
        sh.x = (_Float16)s1; sh.y = (_Float16)s2;
        sh.z = (_Float16)(s3 * 512.0f);          // escape fp16 subnormals
        sh.w = (_Float16)(s4 * 512.0f);
        sumsh[(size_t)((t0 >> 3) + g) * BB + (b0 + bl)] = sh;
    }
}

// ---- per-step delta from frozen (bm, cc) ----
#define PSTEP(W, D)                                                          \
    {                                                                        \
        float w_  = (W);                                                     \
        float aw_ = __builtin_fabsf(w_);                                     \
        float ub_ = aw_ * bm;                                                \
        float Gw_ = fmaf(w_, cc, -ub_);                                      \
        float q_  = bm * w_;                                                 \
        float tt_ = fmaf(0.5f, aw_, q_);                                     \
        D = fmaf(-Gw_, tt_, Gw_);                                            \
    }

// ---------------------------------------------------------------------------
// Kernel 2: s-pilot. 32 blocks x 64. Frozen-macro-8 from fp16 sums; 31 sets
// of 16 macros; 4-buffer rotation, prefetch distance 2 sets. Loads bare;
// HOLDs at consumption (R12-proven). Snapshot after macro 16i+13 -> snap[i].
// ---------------------------------------------------------------------------
__global__ __launch_bounds__(64) void pilot_kernel(
    const uint2* __restrict__ sumsh, float* __restrict__ snap) {

    const int b = blockIdx.x * 64 + threadIdx.x;
    float Z = 0.3f;                               // s/X1
    const uint2* __restrict__ sp = sumsh + b;

    uint2 A[16], B[16], C[16], D[16];

#define PLOAD(BUF, SET)                                                      \
    _Pragma("unroll")                                                        \
    for (int k = 0; k < 16; ++k)                                             \
        BUF[k] = sp[(size_t)((SET) * 16 + k) * BB];

#define HOLDBUF(BUF)                                                         \
    _Pragma("unroll")                                                        \
    for (int k = 0; k < 16; ++k) HOLD2(BUF[k]);

#define PMACRO(U)                                                            \
    {                                                                        \
        uint2 u_ = (U);                                                      \
        half4 h_ = __builtin_bit_cast(half4, u_);                            \
        float s1 = (float)h_.x, s2 = (float)h_.y;                            \
        float s3 = (float)h_.z * 0.001953125f;                               \
        float s4 = (float)h_.w * 0.001953125f;                               \
        float bm = Z - 0.5f;                                                 \
        float cc = fmaf(-bm, bm, 0.75f);                                     \
        float bm2 = bm * bm;                                                 \
        float z2 = Z * Z, z4 = z2 * z2;                                      \
        float pn = (z4 * Z) * K1C;                                           \
        float A_ = fmaf(cc, s1, -(bm * s2));                                 \
        float w1 = fmaf(-0.5f, cc, bm2);                                     \
        float T3 = w1 * s3;                                                  \
        float c2 = cc - 0.5f;                                                \
        float cb = c2 * bm;                                                  \
        float T4 = cb * s4;                                                  \
        float dd = (A_ + T3) - T4;                                           \
        float base = fmaf(pn, -8.0f, Z);                                     \
        Z = base + dd;                                                       \
    }

#define PSET(BUF, J)                                                         \
    {                                                                        \
        HOLDBUF(BUF);                                                        \
        PMACRO(BUF[0]);  PMACRO(BUF[1]);  PMACRO(BUF[2]);  PMACRO(BUF[3]);   \
        PMACRO(BUF[4]);  PMACRO(BUF[5]);  PMACRO(BUF[6]);  PMACRO(BUF[7]);   \
        PMACRO(BUF[8]);  PMACRO(BUF[9]);  PMACRO(BUF[10]); PMACRO(BUF[11]);  \
        PMACRO(BUF[12]); PMACRO(BUF[13]);                                    \
        snap[(size_t)(J) * BB + b] = Z;                                      \
        PMACRO(BUF[14]); PMACRO(BUF[15]);                                    \
    }

    PLOAD(A, 0); PLOAD(B, 1);
    for (int k = 0; k < 7; ++k) {
        int i = 4 * k;
        PLOAD(C, i + 2); __builtin_amdgcn_sched_barrier(0); PSET(A, i);
        PLOAD(D, i + 3); __builtin_amdgcn_sched_barrier(0); PSET(B, i + 1);
        PLOAD(A, i + 4); __builtin_amdgcn_sched_barrier(0); PSET(C, i + 2);
        PLOAD(B, i + 5); __builtin_amdgcn_sched_barrier(0); PSET(D, i + 3);
    }
    // sets 28,29 already in A,B
    PLOAD(C, 30); __builtin_amdgcn_sched_barrier(0);
    PSET(A, 28); PSET(B, 29); PSET(C, 30);

#undef PSET
#undef PMACRO
#undef HOLDBUF
#undef PLOAD
}

// ---------------------------------------------------------------------------
// Kernel 3: fused segmented scan + 30-tap conv + qr add. 1024 blocks =
// 32 segments x 32 b-groups, 64 threads. Loads bare; holds at consumption.
// ---------------------------------------------------------------------------
__global__ __launch_bounds__(64) void seg_kernel(
    const uint2* __restrict__ wTh, const float* __restrict__ snap,
    const float* __restrict__ qr, const float* __restrict__ uh1,
    const float* __restrict__ uh2, const float* __restrict__ x1p,
    float* __restrict__ outp) {
    __shared__ float tile[64 * 65];
    const int lane = threadIdx.x;
    const int sig = blockIdx.x >> 5;              // 0..31
    const int b0 = (blockIdx.x & 31) * 64;
    const int b = b0 + lane;
    const int T0 = sig << 7;                      // 128*sig
    const float X1 = fminf(fmaxf(x1p[0], 1.0f / 2000.0f), 1.0f) * 2000.0f;

    float WX[30];
#pragma unroll
    for (int k = 0; k < 30; ++k)
        WX[k] = X1 * fmaf(0.9f, uh1[k], 0.1f * uh2[k]);

    float Z = 0.3f;
    if (sig > 0) Z = snap[(size_t)(sig - 1) * BB + b];
    float zs0 = Z * Z, z40 = zs0 * zs0;
    float pn0 = (z40 * Z) * K1C;
    float pnL1 = pn0, pnL2 = pn0, pnL3 = pn0, pnL4 = pn0;

    float ring[32];
#pragma unroll
    for (int i = 0; i < 32; ++i) ring[i] = 0.0f;

    const int R0 = 32 * sig - 4;                  // first wTh row (t=T0-16)
    const uint2* __restrict__ vp = wTh + b;
    uint2 A[8], B[8];

#define LOADC(BUF, C)                                                        \
    _Pragma("unroll")                                                        \
    for (int k = 0; k < 8; ++k) {                                            \
        int rq = R0 + 8 * (C) + k;                                           \
        BUF[k] = (rq >= 0 && rq < TQ) ? vp[(size_t)rq * BB]                  \
                                      : make_uint2(0u, 0u);                  \
    }

#define HOLDC(BUF)                                                           \
    _Pragma("unroll")                                                        \
    for (int k = 0; k < 8; ++k) HOLD2(BUF[k]);

#define EMIT(C, MM, I)                                                       \
    {                                                                        \
        float acc = 0.0f;                                                    \
        _Pragma("unroll")                                                    \
        for (int k = 0; k < 30; ++k)                                         \
            acc = fmaf(WX[k], ring[(4 * (MM) + (I) + 3 + k) & 31], acc);     \
        tile[((32 * (C) + 4 * (MM) + (I) - 15) & 63) * 65 + lane] = acc;     \
    }

#define SMACRO(U4, MM, C)                                                    \
    {                                                                        \
        uint2 u4_ = (U4);                                                    \
        half4 h4_ = __builtin_bit_cast(half4, u4_);                          \
        float4 v4;                                                           \
        v4.x = (float)h4_.x; v4.y = (float)h4_.y;                            \
        v4.z = (float)h4_.z; v4.w = (float)h4_.w;                            \
        float bm = Z - 0.5f;                                                 \
        float cc = fmaf(-bm, bm, 0.75f);                                     \
        float L12 = pnL1 + pnL2, L123 = L12 + pnL3, L1234 = L123 + pnL4;     \
        float e1 = Z - pnL1, e2 = Z - L12, e3 = Z - L123, e4 = Z - L1234;    \
        float d1, d2, d3, d4;                                                \
        PSTEP(v4.x, d1); PSTEP(v4.y, d2); PSTEP(v4.z, d3); PSTEP(v4.w, d4);  \
        float p2 = d1 + d2, t34 = d3 + d4;                                   \
        float p3 = p2 + d3, p4 = p2 + t34;                                   \
        float z1 = Z + d1, z2 = e1 + p2, z3 = e2 + p3, z4 = e3 + p4;         \
        Z = e4 + p4;                                                         \
        float a1 = z1 * z1, a2 = z2 * z2, a3 = z3 * z3, a4 = z4 * z4;        \
        float g1 = a1 * a1, g2 = a2 * a2, g3 = a3 * a3, g4 = a4 * a4;        \
        float h1 = z1 * K1C, h2 = z2 * K1C, h3 = z3 * K1C, h4 = z4 * K1C;    \
        float n1 = g1 * h1, n2 = g2 * h2, n3 = g3 * h3, n4 = g4 * h4;        \
        float pr1 = fmaxf(v4.x - d1, 0.0f) + n1;                             \
        float pr2 = fmaxf(v4.y - d2, 0.0f) + n2;                             \
        float pr3 = fmaxf(v4.z - d3, 0.0f) + n3;                             \
        float pr4 = fmaxf(v4.w - d4, 0.0f) + n4;                             \
        pnL1 = n1; pnL2 = n2; pnL3 = n3; pnL4 = n4;                          \
        int tb_ = T0 - 16 + 32 * (C) + 4 * (MM);                             \
        pr1 = ((unsigned)(tb_ + 0) < (unsigned)TT) ? pr1 : 0.0f;             \
        pr2 = ((unsigned)(tb_ + 1) < (unsigned)TT) ? pr2 : 0.0f;             \
        pr3 = ((unsigned)(tb_ + 2) < (unsigned)TT) ? pr3 : 0.0f;             \
        pr4 = ((unsigned)(tb_ + 3) < (unsigned)TT) ? pr4 : 0.0f;             \
        ring[(4 * (MM) + 0) & 31] = pr1;                                     \
        ring[(4 * (MM) + 1) & 31] = pr2;                                     \
        ring[(4 * (MM) + 2) & 31] = pr3;                                     \
        ring[(4 * (MM) + 3) & 31] = pr4;                                     \
        EMIT(C, MM, 0); EMIT(C, MM, 1); EMIT(C, MM, 2); EMIT(C, MM, 3);      \
    }

#define COMPUTE(BUF, C)                                                      \
    HOLDC(BUF);                                                              \
    SMACRO(BUF[0], 0, C); SMACRO(BUF[1], 1, C);                              \
    SMACRO(BUF[2], 2, C); SMACRO(BUF[3], 3, C);                              \
    SMACRO(BUF[4], 4, C); SMACRO(BUF[5], 5, C);                              \
    SMACRO(BUF[6], 6, C); SMACRO(BUF[7], 7, C);

#define FLUSH(J, RLO, RHI)                                                   \
    {                                                                        \
        int tb = T0 - 16 + 32 * (J);                                         \
        int RB = 32 * ((J) & 1);                                             \
        int a4 = (lane & 7) * 4;                                             \
        int tq = tb + a4;                                                    \
        int tqc = min(max(tq, 0), TT - 4);                                   \
        float4 q4 = *reinterpret_cast<const float4*>(qr + tqc);              \
        bool ok = (a4 >= (RLO)) && (a4 < (RHI));                             \
        _Pragma("unroll")                                                    \
        for (int r2 = 0; r2 < 8; ++r2) {                                     \
            int bl = (lane >> 3) + 8 * r2;                                   \
            float v0 = tile[(RB + a4 + 0) * 65 + bl];                        \
            float v1 = tile[(RB + a4 + 1) * 65 + bl];                        \
            float v2 = tile[(RB + a4 + 2) * 65 + bl];                        \
            float v3 = tile[(RB + a4 + 3) * 65 + bl];                        \
            if (ok) {                                                        \
                float4 o = make_float4(q4.x + v0, q4.y + v1,                 \
                                       q4.z + v2, q4.w + v3);                \
                *reinterpret_cast<float4*>(                                  \
                    outp + (size_t)(b0 + bl) * TT + tq) = o;                 \
            }                                                                \
        }                                                                    \
    }

    LOADC(A, 0); LOADC(B, 1);
    __builtin_amdgcn_sched_barrier(0);
    COMPUTE(A, 0);
    LOADC(A, 2);
    __builtin_amdgcn_sched_barrier(0);
    COMPUTE(B, 1);
    __syncthreads(); FLUSH(0, 16, 32);
    LOADC(B, 3);
    __builtin_amdgcn_sched_barrier(0);
    COMPUTE(A, 2);
    __syncthreads(); FLUSH(1, 0, 32);
    LOADC(A, 4);
    __builtin_amdgcn_sched_barrier(0);
    COMPUTE(B, 3);
    __syncthreads(); FLUSH(2, 0, 32);
    COMPUTE(A, 4);
    __syncthreads(); FLUSH(3, 0, 32); FLUSH(4, 0, 16);

#undef FLUSH
#undef COMPUTE
#undef SMACRO
#undef EMIT
#undef HOLDC
#undef LOADC
}

// ---------------------------------------------------------------------------
extern "C" void kernel_launch(void* const* d_in, const int* in_sizes, int n_in,
                              void* d_out, int out_size, void* d_ws, size_t ws_size,
                              hipStream_t stream) {
    const float* inp = (const float*)d_in[0];
    const float* x1  = (const float*)d_in[1];
    const float* x2  = (const float*)d_in[2];
    const float* x3  = (const float*)d_in[3];
    const float* uh1 = (const float*)d_in[4];
    const float* uh2 = (const float*)d_in[5];
    float* out = (float*)d_out;

    char* ws = (char*)d_ws;
    half4* wTh   = (half4*)ws;                                // 16.78 MB
    half4* sumsh = (half4*)(ws + (size_t)TQ * BB * 8);        // 8.39 MB
    float* qrp   = (float*)(ws + (size_t)TQ * BB * 8 + (size_t)512 * BB * 8);
    float* snap  = qrp + TT;                                  // 31*BB floats

    precompute_kernel<<<(TT / 64) * (BB / 64) + 1, 256, 0, stream>>>(
        inp, x1, x2, x3, wTh, sumsh, qrp);
    pilot_kernel<<<32, 64, 0, stream>>>((const uint2*)sumsh, snap);
    seg_kernel<<<1024, 64, 0, stream>>>((const uint2*)wTh, snap, qrp,
                                        uh1, uh2, x1, out);
}

// Round 18
// 75.423 us; speedup vs baseline: 1.1111x; 1.1111x over previous
//
#include <hip/hip_runtime.h>

#define BB 2048
#define TT 4096
#define TQ (TT / 4)   // 1024 packed rows
#define K1C 0.00975461f   // 0.25*(4/9)^4  (Perc/X1 = K1C*z^5)

typedef __attribute__((ext_vector_type(4))) _Float16 half4;

// keep-alive. MUST be applied at CONSUMPTION time (R11: holding at load time
// forces vmcnt-wait per load and serializes everything).
#define HOLD2(U) asm volatile("" : "+v"((U).x), "+v"((U).y))
#define HOLD4(V) asm volatile("" : "+v"((V).x), "+v"((V).y), "+v"((V).z), "+v"((V).w))

// ---------------------------------------------------------------------------
// Kernel 1 (R16-proven): block 0 = r-chain closed form (X2==0: u=rn^-4 is
// exactly linear -> rn_t=(u0+t)^-1/4, fully parallel). Blocks 1..2048: pet
// precompute, fp16 LDS tile, packed-transposed wTh[tq][b] + per-8 sums fp16.
// ---------------------------------------------------------------------------
__global__ __launch_bounds__(256) void precompute_kernel(
    const float* __restrict__ inp, const float* __restrict__ x1p,
    const float* __restrict__ x2p, const float* __restrict__ x3p,
    half4* __restrict__ wTh, half4* __restrict__ sumsh,
    float* __restrict__ qr) {

    if (blockIdx.x == 0) {
        float X2 = x2p[0] * 40.0f - 20.0f;
        float X3 = fminf(fmaxf(x3p[0], 1.0f / 300.0f), 1.0f) * 300.0f;
        if (X2 == 0.0f) {
            float rn0 = 0.7f;
            float rn2 = rn0 * rn0;
            float u0  = 1.0f / (rn2 * rn2);      // 0.7^-4
#pragma unroll
            for (int i = 0; i < 16; ++i) {
                int t = threadIdx.x + 256 * i;
                float v  = u0 + (float)t;
                float q  = __builtin_amdgcn_rcpf(v);
                float h  = fmaf(q, fmaf(q, fmaf(q, -0.09521484f,
                                  0.1171875f), -0.15625f), 0.25f);
                float w  = q * h;
                float rn = __builtin_amdgcn_rsqf(sqrtf(v));   // v^-1/4
                qr[t] = (X3 * rn) * w;
            }
        } else if (threadIdx.x == 0) {
            float invX3 = 1.0f / X3;
            float r = 0.7f * X3;
            for (int t = 0; t < TT; ++t) {
                float rx  = r * invX3;
                float rx3 = rx * rx * rx;
                float pw  = rx3 * sqrtf(rx);              // rx^3.5
                float r1  = fmaxf(fmaf(X2, pw, r), 0.0f);
                float m   = r1 * invX3;
                float m2  = m * m;
                float z   = fmaf(m2, m2, 1.0f);
                float u   = __builtin_amdgcn_rsqf(sqrtf(z)); // z^-0.25
                float Qr  = r1 * (1.0f - u);
                r = fminf(r1 * u, X3);
                qr[t] = Qr;
            }
        }
        return;
    }

    __shared__ _Float16 ldsh[64 * 68];           // 8.7 KB (fp16, 68-stride)
    const int bid = blockIdx.x - 1;
    const int tiles_t = TT / 64;                 // 64
    const int t0 = (bid % tiles_t) * 64;
    const int b0 = (bid / tiles_t) * 64;
    const float X1 = fminf(fmaxf(x1p[0], 1.0f / 2000.0f), 1.0f) * 2000.0f;
    const float invX1 = 1.0f / X1;

    // ---- phase 1: ALL loads first (12 float4 in flight), then compute ----
    const int q = threadIdx.x & 15;
    const int r = threadIdx.x >> 4;              // 0..15
    float4 L[12];
#pragma unroll
    for (int i = 0; i < 4; ++i) {
        int bl = r + 16 * i;
        size_t e = ((size_t)(b0 + bl) * TT + (t0 + 4 * q)) * 3; // %4 == 0
        const float4* src = reinterpret_cast<const float4*>(inp + e);
        L[3 * i + 0] = src[0];
        L[3 * i + 1] = src[1];
        L[3 * i + 2] = src[2];
    }
    __builtin_amdgcn_sched_barrier(0);
#pragma unroll
    for (int i = 0; i < 4; ++i) {
        int bl = r + 16 * i;
        HOLD4(L[3 * i + 0]); HOLD4(L[3 * i + 1]); HOLD4(L[3 * i + 2]);
        float4 A4 = L[3 * i + 0], B4 = L[3 * i + 1], C4 = L[3 * i + 2];
        // elements: p0 t0 d0 p1 | t1 d1 p2 t2 | d2 p3 t3 d3
        float pk[4], tk[4], dk[4];
        pk[0] = A4.x; tk[0] = A4.y; dk[0] = A4.z;
        pk[1] = A4.w; tk[1] = B4.x; dk[1] = B4.y;
        pk[2] = B4.z; tk[2] = B4.w; dk[2] = C4.x;
        pk[3] = C4.y; tk[3] = C4.z; dk[3] = C4.w;
        half4 hw;
#pragma unroll
        for (int j = 0; j < 4; ++j) {
            float tt = tk[j];
            float u1 = __builtin_amdgcn_rcpf(tt + 237.3f);
            float u2 = __builtin_amdgcn_rcpf(tt + 273.2f);
            float ex = exp2f((24.9586242f * tt) * u1);    // e^(17.3t/(t+237.3))
            float pet = (436.9872f * dk[j]) * (ex * u2);  // 29.8*24*0.611
            float w = (pk[j] - pet) * invX1;     // sign encodes cond
            if (j == 0) hw.x = (_Float16)w; else if (j == 1) hw.y = (_Float16)w;
            else if (j == 2) hw.z = (_Float16)w; else hw.w = (_Float16)w;
        }
        *reinterpret_cast<half4*>(&ldsh[bl * 68 + 4 * q]) = hw;
    }
    __syncthreads();

    // ---- phase 2: wTh copy (already fp16) + pilot sums ----
    const int tl = threadIdx.x & 63;
    const int r4 = threadIdx.x >> 6;             // 0..3
    const int tq0 = t0 >> 2;
    for (int i = 0; i < 4; ++i) {
        int tr = i * 4 + r4;
        half4 hv = *reinterpret_cast<const half4*>(&ldsh[tl * 68 + tr * 4]);
        wTh[(size_t)(tq0 + tr) * BB + (b0 + tl)] = hv;
    }
#pragma unroll
    for (int i = 0; i < 2; ++i) {
        int job = threadIdx.x + 256 * i;         // 0..511
        int bl = job & 63, g = job >> 6;
        half4 ha = *reinterpret_cast<const half4*>(&ldsh[bl * 68 + g * 8]);
        half4 hb = *reinterpret_cast<const half4*>(&ldsh[bl * 68 + g * 8 + 4]);
        float s1 = 0.f, s2 = 0.f, s3 = 0.f, s4 = 0.f;
#pragma unroll
        for (int j = 0; j < 8; ++j) {
            float w = (j < 4) ? (float)((j == 0) ? ha.x : (j == 1) ? ha.y :
                                        (j == 2) ? ha.z : ha.w)
                              : (float)((j == 4) ? hb.x : (j == 5) ? hb.y :
                                        (j == 6) ? hb.z : hb.w);
            float a = fabsf(w);
            s1 += w; s2 += a; s3 += w * a; s4 += w * w;
        }
        half4 sh;
        sh.x = (_Float16)s1; sh.y = (_Float16)s2;
        sh.z = (_Float16)(s3 * 512.0f);          // escape fp16 subnormals
        sh.w = (_Float16)(s4 * 512.0f);
        sumsh[(size_t)((t0 >> 3) + g) * BB + (b0 + bl)] = sh;
    }
}

// ---- per-step delta from frozen (bm, cc) ----
#define PSTEP(W, D)                                                          \
    {                                                                        \
        float w_  = (W);                                                     \
        float aw_ = __builtin_fabsf(w_);                                     \
        float ub_ = aw_ * bm;                                                \
        float Gw_ = fmaf(w_, cc, -ub_);                                      \
        float q_  = bm * w_;                                                 \
        float tt_ = fmaf(0.5f, aw_, q_);                                     \
        D = fmaf(-Gw_, tt_, Gw_);                                            \
    }

// ---------------------------------------------------------------------------
// Kernel 2: s-pilot. 32 blocks x 64. Frozen-macro-8 from fp16 sums; 32 sets
// of 16 macros; 4-buffer rotation, prefetch distance 2 sets; loads bare,
// HOLDs at consumption (R12-proven). TWO snapshots per set (after macros 6
// and 14): snap[2J] = Z at t=128J+48, snap[2J+1] = Z at t=128J+112 -- i.e.
// snap[s-1] = state at t = 64s-16 for 64-step segments.
// ---------------------------------------------------------------------------
__global__ __launch_bounds__(64) void pilot_kernel(
    const uint2* __restrict__ sumsh, float* __restrict__ snap) {

    const int b = blockIdx.x * 64 + threadIdx.x;
    float Z = 0.3f;                               // s/X1
    const uint2* __restrict__ sp = sumsh + b;

    uint2 A[16], B[16], C[16], D[16];

#define PLOAD(BUF, SET)                                                      \
    _Pragma("unroll")                                                        \
    for (int k = 0; k < 16; ++k)                                             \
        BUF[k] = sp[(size_t)((SET) * 16 + k) * BB];

#define HOLDBUF(BUF)                                                         \
    _Pragma("unroll")                                                        \
    for (int k = 0; k < 16; ++k) HOLD2(BUF[k]);

#define PMACRO(U)                                                            \
    {                                                                        \
        uint2 u_ = (U);                                                      \
        half4 h_ = __builtin_bit_cast(half4, u_);                            \
        float s1 = (float)h_.x, s2 = (float)h_.y;                            \
        float s3 = (float)h_.z * 0.001953125f;                               \
        float s4 = (float)h_.w * 0.001953125f;                               \
        float bm = Z - 0.5f;                                                 \
        float cc = fmaf(-bm, bm, 0.75f);                                     \
        float bm2 = bm * bm;                                                 \
        float z2 = Z * Z, z4 = z2 * z2;                                      \
        float pn = (z4 * Z) * K1C;                                           \
        float A_ = fmaf(cc, s1, -(bm * s2));                                 \
        float w1 = fmaf(-0.5f, cc, bm2);                                     \
        float T3 = w1 * s3;                                                  \
        float c2 = cc - 0.5f;                                                \
        float cb = c2 * bm;                                                  \
        float T4 = cb * s4;                                                  \
        float dd = (A_ + T3) - T4;                                           \
        float base = fmaf(pn, -8.0f, Z);                                     \
        Z = base + dd;                                                       \
    }

#define PSET(BUF, J)                                                         \
    {                                                                        \
        HOLDBUF(BUF);                                                        \
        PMACRO(BUF[0]);  PMACRO(BUF[1]);  PMACRO(BUF[2]);                    \
        PMACRO(BUF[3]);  PMACRO(BUF[4]);  PMACRO(BUF[5]);                    \
        snap[(size_t)(2 * (J)) * BB + b] = Z;                                \
        PMACRO(BUF[6]);  PMACRO(BUF[7]);  PMACRO(BUF[8]);  PMACRO(BUF[9]);   \
        PMACRO(BUF[10]); PMACRO(BUF[11]); PMACRO(BUF[12]); PMACRO(BUF[13]);  \
        snap[(size_t)(2 * (J) + 1) * BB + b] = Z;                            \
        PMACRO(BUF[14]); PMACRO(BUF[15]);                                    \
    }

    PLOAD(A, 0); PLOAD(B, 1);
    for (int k = 0; k < 7; ++k) {
        int i = 4 * k;
        PLOAD(C, i + 2); __builtin_amdgcn_sched_barrier(0); PSET(A, i);
        PLOAD(D, i + 3); __builtin_amdgcn_sched_barrier(0); PSET(B, i + 1);
        PLOAD(A, i + 4); __builtin_amdgcn_sched_barrier(0); PSET(C, i + 2);
        PLOAD(B, i + 5); __builtin_amdgcn_sched_barrier(0); PSET(D, i + 3);
    }
    // after loop: sets 0..27 done; A = set 28, B = set 29
    PLOAD(C, 30); __builtin_amdgcn_sched_barrier(0); PSET(A, 28);
    PLOAD(D, 31); __builtin_amdgcn_sched_barrier(0); PSET(B, 29);
    PSET(C, 30); PSET(D, 31);

#undef PSET
#undef PMACRO
#undef HOLDBUF
#undef PLOAD
}

// ---------------------------------------------------------------------------
// Kernel 3: fused segmented scan + 30-tap conv + qr add.
// 2048 jobs = 64 segments (64 steps) x 32 b-groups; 2 jobs per 128-thread
// block (wave w = job 2*blockIdx+w) -> 8 waves/CU (2x the TLP of R16's
// 1-wave blocks). Per job: 3 chunks (96 steps = 16 warm-up + 64 out + 16
// tail), ring conv, LDS double-tile flush. Loads bare; holds at consumption.
// ---------------------------------------------------------------------------
__global__ __launch_bounds__(128) void seg_kernel(
    const uint2* __restrict__ wTh, const float* __restrict__ snap,
    const float* __restrict__ qr, const float* __restrict__ uh1,
    const float* __restrict__ uh2, const float* __restrict__ x1p,
    float* __restrict__ outp) {
    __shared__ float tile2[2][64 * 65];
    const int wid  = threadIdx.x >> 6;
    const int lane = threadIdx.x & 63;
    float* tile_ = tile2[wid];
    const int job = (blockIdx.x << 1) | wid;
    const int sig = job >> 5;                     // 0..63
    const int b0  = (job & 31) * 64;
    const int b   = b0 + lane;
    const int T0  = sig << 6;                     // 64*sig
    const float X1 = fminf(fmaxf(x1p[0], 1.0f / 2000.0f), 1.0f) * 2000.0f;

    float WX[30];
#pragma unroll
    for (int k = 0; k < 30; ++k)
        WX[k] = X1 * fmaf(0.9f, uh1[k], 0.1f * uh2[k]);

    float Z = 0.3f;
    if (sig > 0) Z = snap[(size_t)(sig - 1) * BB + b];
    float zs0 = Z * Z, z40 = zs0 * zs0;
    float pn0 = (z40 * Z) * K1C;
    float pnL1 = pn0, pnL2 = pn0, pnL3 = pn0, pnL4 = pn0;

    float ring[32];
#pragma unroll
    for (int i = 0; i < 32; ++i) ring[i] = 0.0f;

    const int R0 = 16 * sig - 4;                  // first wTh row (t=T0-16)
    const uint2* __restrict__ vp = wTh + b;
    uint2 A[8], B[8];

#define LOADC(BUF, C)                                                        \
    _Pragma("unroll")                                                        \
    for (int k = 0; k < 8; ++k) {                                            \
        int rq = R0 + 8 * (C) + k;                                           \
        BUF[k] = (rq >= 0 && rq < TQ) ? vp[(size_t)rq * BB]                  \
                                      : make_uint2(0u, 0u);                  \
    }

#define HOLDC(BUF)                                                           \
    _Pragma("unroll")                                                        \
    for (int k = 0; k < 8; ++k) HOLD2(BUF[k]);

#define EMIT(C, MM, I)                                                       \
    {                                                                        \
        float acc = 0.0f;                                                    \
        _Pragma("unroll")                                                    \
        for (int k = 0; k < 30; ++k)                                         \
            acc = fmaf(WX[k], ring[(4 * (MM) + (I) + 3 + k) & 31], acc);     \
        tile_[((32 * (C) + 4 * (MM) + (I) - 15) & 63) * 65 + lane] = acc;    \
    }

#define SMACRO(U4, MM, C)                                                    \
    {                                                                        \
        uint2 u4_ = (U4);                                                    \
        half4 h4_ = __builtin_bit_cast(half4, u4_);                          \
        float4 v4;                                                           \
        v4.x = (float)h4_.x; v4.y = (float)h4_.y;                            \
        v4.z = (float)h4_.z; v4.w = (float)h4_.w;                            \
        float bm = Z - 0.5f;                                                 \
        float cc = fmaf(-bm, bm, 0.75f);                                     \
        float L12 = pnL1 + pnL2, L123 = L12 + pnL3, L1234 = L123 + pnL4;     \
        float e1 = Z - pnL1, e2 = Z - L12, e3 = Z - L123, e4 = Z - L1234;    \
        float d1, d2, d3, d4;                                                \
        PSTEP(v4.x, d1); PSTEP(v4.y, d2); PSTEP(v4.z, d3); PSTEP(v4.w, d4);  \
        float p2 = d1 + d2, t34 = d3 + d4;                                   \
        float p3 = p2 + d3, p4 = p2 + t34;                                   \
        float z1 = Z + d1, z2 = e1 + p2, z3 = e2 + p3, z4 = e3 + p4;         \
        Z = e4 + p4;                                                         \
        float a1 = z1 * z1, a2 = z2 * z2, a3 = z3 * z3, a4 = z4 * z4;        \
        float g1 = a1 * a1, g2 = a2 * a2, g3 = a3 * a3, g4 = a4 * a4;        \
        float h1 = z1 * K1C, h2 = z2 * K1C, h3 = z3 * K1C, h4 = z4 * K1C;    \
        float n1 = g1 * h1, n2 = g2 * h2, n3 = g3 * h3, n4 = g4 * h4;        \
        float pr1 = fmaxf(v4.x - d1, 0.0f) + n1;                             \
        float pr2 = fmaxf(v4.y - d2, 0.0f) + n2;                             \
        float pr3 = fmaxf(v4.z - d3, 0.0f) + n3;                             \
        float pr4 = fmaxf(v4.w - d4, 0.0f) + n4;                             \
        pnL1 = n1; pnL2 = n2; pnL3 = n3; pnL4 = n4;                          \
        int tb_ = T0 - 16 + 32 * (C) + 4 * (MM);                             \
        pr1 = ((unsigned)(tb_ + 0) < (unsigned)TT) ? pr1 : 0.0f;             \
        pr2 = ((unsigned)(tb_ + 1) < (unsigned)TT) ? pr2 : 0.0f;             \
        pr3 = ((unsigned)(tb_ + 2) < (unsigned)TT) ? pr3 : 0.0f;             \
        pr4 = ((unsigned)(tb_ + 3) < (unsigned)TT) ? pr4 : 0.0f;             \
        ring[(4 * (MM) + 0) & 31] = pr1;                                     \
        ring[(4 * (MM) + 1) & 31] = pr2;                                     \
        ring[(4 * (MM) + 2) & 31] = pr3;                                     \
        ring[(4 * (MM) + 3) & 31] = pr4;                                     \
        EMIT(C, MM, 0); EMIT(C, MM, 1); EMIT(C, MM, 2); EMIT(C, MM, 3);      \
    }

#define COMPUTE(BUF, C)                                                      \
    HOLDC(BUF);                                                              \
    SMACRO(BUF[0], 0, C); SMACRO(BUF[1], 1, C);                              \
    SMACRO(BUF[2], 2, C); SMACRO(BUF[3], 3, C);                              \
    SMACRO(BUF[4], 4, C); SMACRO(BUF[5], 5, C);                              \
    SMACRO(BUF[6], 6, C); SMACRO(BUF[7], 7, C);

#define FLUSH(J, RLO, RHI)                                                   \
    {                                                                        \
        int tb = T0 - 16 + 32 * (J);                                         \
        int RB = 32 * ((J) & 1);                                             \
        int a4 = (lane & 7) * 4;                                             \
        int tq = tb + a4;                                                    \
        int tqc = min(max(tq, 0), TT - 4);                                   \
        float4 q4 = *reinterpret_cast<const float4*>(qr + tqc);              \
        bool ok = (a4 >= (RLO)) && (a4 < (RHI));                             \
        _Pragma("unroll")                                                    \
        for (int r2 = 0; r2 < 8; ++r2) {                                     \
            int bl = (lane >> 3) + 8 * r2;                                   \
            float v0 = tile_[(RB + a4 + 0) * 65 + bl];                       \
            float v1 = tile_[(RB + a4 + 1) * 65 + bl];                       \
            float v2 = tile_[(RB + a4 + 2) * 65 + bl];                       \
            float v3 = tile_[(RB + a4 + 3) * 65 + bl];                       \
            if (ok) {                                                        \
                float4 o = make_float4(q4.x + v0, q4.y + v1,                 \
                                       q4.z + v2, q4.w + v3);                \
                *reinterpret_cast<float4*>(                                  \
                    outp + (size_t)(b0 + bl) * TT + tq) = o;                 \
            }                                                                \
        }                                                                    \
    }

    // 3 chunks: t in [T0-16, T0+80); outputs [T0, T0+64)
    LOADC(A, 0); LOADC(B, 1);
    __builtin_amdgcn_sched_barrier(0);
    COMPUTE(A, 0);
    LOADC(A, 2);
    __builtin_amdgcn_sched_barrier(0);
    COMPUTE(B, 1);
    __syncthreads(); FLUSH(0, 16, 32);
    __syncthreads();                 // FLUSH(0) rows reused by chunk 2
    COMPUTE(A, 2);
    __syncthreads(); FLUSH(1, 0, 32); FLUSH(2, 0, 16);

#undef FLUSH
#undef COMPUTE
#undef SMACRO
#undef EMIT
#undef HOLDC
#undef LOADC
}

// ---------------------------------------------------------------------------
extern "C" void kernel_launch(void* const* d_in, const int* in_sizes, int n_in,
                              void* d_out, int out_size, void* d_ws, size_t ws_size,
                              hipStream_t stream) {
    const float* inp = (const float*)d_in[0];
    const float* x1  = (const float*)d_in[1];
    const float* x2  = (const float*)d_in[2];
    const float* x3  = (const float*)d_in[3];
    const float* uh1 = (const float*)d_in[4];
    const float* uh2 = (const float*)d_in[5];
    float* out = (float*)d_out;

    char* ws = (char*)d_ws;
    half4* wTh   = (half4*)ws;                                // 16.78 MB
    half4* sumsh = (half4*)(ws + (size_t)TQ * BB * 8);        // 8.39 MB
    float* qrp   = (float*)(ws + (size_t)TQ * BB * 8 + (size_t)512 * BB * 8);
    float* snap  = qrp + TT;                                  // 64*BB floats

    precompute_kernel<<<(TT / 64) * (BB / 64) + 1, 256, 0, stream>>>(
        inp, x1, x2, x3, wTh, sumsh, qrp);
    pilot_kernel<<<32, 64, 0, stream>>>((const uint2*)sumsh, snap);
    seg_kernel<<<1024, 128, 0, stream>>>((const uint2*)wTh, snap, qrp,
                                         uh1, uh2, x1, out);
}